// Round 12
// baseline (256.148 us; speedup 1.0000x reference)
//
#include <hip/hip_runtime.h>
#include <math.h>

#define DDIM 4096
#define NEXP 64
#define KSPLIT 16
#define KRANGE 256  // k per block
#define NKT 8       // 32-k tiles per block
#define TGTOK 1024  // tokens per block
#define NSTEP 32    // token steps of 32
#define XCH 32768   // one x buffer: 32 tok x 1KB
#define NTOK 16384

typedef short s16x8 __attribute__((ext_vector_type(8)));
typedef float f32x4 __attribute__((ext_vector_type(4)));

__device__ __forceinline__ unsigned cvt_pk_bf16(float a, float b) {
  unsigned r;
  asm("v_cvt_pk_bf16_f32 %0, %1, %2" : "=v"(r) : "v"(a), "v"(b));
  return r;
}

__device__ __forceinline__ void split2(float a, float b, unsigned& H,
                                       unsigned& M, unsigned& L) {
  H = cvt_pk_bf16(a, b);
  float h0 = __uint_as_float(H << 16);
  float h1 = __uint_as_float(H & 0xffff0000u);
  float r0 = a - h0, r1 = b - h1;
  M = cvt_pk_bf16(r0, r1);
  float m0 = __uint_as_float(M << 16);
  float m1 = __uint_as_float(M & 0xffff0000u);
  L = cvt_pk_bf16(r0 - m0, r1 - m1);
}

union U8 { unsigned u[4]; s16x8 v; };
__device__ __forceinline__ s16x8 pack8(const unsigned* a) {
  U8 t;
  t.u[0] = a[0]; t.u[1] = a[1]; t.u[2] = a[2]; t.u[3] = a[3];
  return t.v;
}

#define MFMA(A, B, C) __builtin_amdgcn_mfma_f32_16x16x32_bf16(A, B, C, 0, 0, 0)

// stage 32 tokens' contiguous 1KB k-slices; one DMA per token; source
// chunk-XOR-swizzled (rule #21) so swizzled LDS reads are conflict-balanced.
__device__ __forceinline__ void stage_tok(const float* __restrict__ x,
                                          char* dst, size_t tokbase, int ks,
                                          int step, int wv, int lane) {
#pragma unroll
  for (int j = 0; j < 4; ++j) {
    const int t32 = wv * 4 + j;
    const float* src = x + (tokbase + (size_t)step * 32 + t32) * DDIM +
                       ks * KRANGE + ((lane ^ (t32 & 7)) << 2);
    __builtin_amdgcn_global_load_lds(
        (const __attribute__((address_space(1))) void*)src,
        (__attribute__((address_space(3))) void*)(dst + t32 * 1024), 16, 0, 0);
  }
}

// 256 blocks (16 ks x 16 tg), 512 thr (8 waves). Wave (th = wv>>2, eq = wv&3):
// 16 tokens x 16 experts x 256 k per step. w fragments PERSISTENT in VGPRs
// (24 frags = 96 VGPR, loaded once) -> zero w traffic in loop. x staged via
// global_load_lds, depth-2 prefetch, triple buffer, counted vmcnt(12).
// Per-step 16x16 logit partials written to parts[ks][token][expert].
__global__ __launch_bounds__(512, 2) void moe_gemm(
    const float* __restrict__ x, const ushort* __restrict__ wf,
    float* __restrict__ parts) {
  __shared__ char xls[3 * XCH];  // 96 KB
  const int tid = threadIdx.x;
  const int lane = tid & 63;
  const int wv = tid >> 6;  // 0..7
  const int th = wv >> 2;   // token half of the 32-token step chunk
  const int eq = wv & 3;    // expert quarter
  const int bid = blockIdx.x;
  const int ks = bid & 15;
  const size_t tokbase = (size_t)(bid >> 4) * TGTOK;

  // prologue: 2 steps of x in flight FIRST (oldest), then w-frag loads
  stage_tok(x, xls, tokbase, ks, 0, wv, lane);
  stage_tok(x, xls + XCH, tokbase, ks, 1, wv, lane);

  s16x8 wr[NKT][3];  // persistent w fragments (static indexing only)
  {
    const ushort* wbase =
        wf + ((size_t)(ks * NKT) * 12 + eq * 3) * 512 + lane * 8;
#pragma unroll
    for (int kt = 0; kt < NKT; ++kt)
#pragma unroll
      for (int l = 0; l < 3; ++l)
        wr[kt][l] = *(const s16x8*)(wbase + ((size_t)kt * 12 + l) * 512);
  }

  const int trd = th * 16 + (lane & 15);  // token read by this lane
  const int sz = trd & 7;
  const int coff = (lane >> 4) * 2;  // k-octet chunk offset

#pragma unroll 1
  for (int i = 0; i < NSTEP; ++i) {
    if (i < NSTEP - 2) {
      stage_tok(x, xls + ((i + 2) % 3) * XCH, tokbase, ks, i + 2, wv, lane);
      asm volatile("s_waitcnt vmcnt(12)" ::: "memory");
    } else if (i == NSTEP - 2) {
      asm volatile("s_waitcnt vmcnt(8)" ::: "memory");
    } else {
      asm volatile("s_waitcnt vmcnt(4)" ::: "memory");
    }
    __builtin_amdgcn_s_barrier();

    const char* xrow = xls + (i % 3) * XCH + trd * 1024;
    f32x4 accH = {0.f, 0.f, 0.f, 0.f}, accC = {0.f, 0.f, 0.f, 0.f};
#pragma unroll
    for (int kt = 0; kt < NKT; ++kt) {
      const int c0 = kt * 8 + coff;
      const f32x4 xa = *(const f32x4*)(xrow + ((c0 ^ sz) << 4));
      const f32x4 xv = *(const f32x4*)(xrow + (((c0 + 1) ^ sz) << 4));
      unsigned AH[4], AM[4], AL[4];
      split2(xa[0], xa[1], AH[0], AM[0], AL[0]);
      split2(xa[2], xa[3], AH[1], AM[1], AL[1]);
      split2(xv[0], xv[1], AH[2], AM[2], AL[2]);
      split2(xv[2], xv[3], AH[3], AM[3], AL[3]);
      const s16x8 ah = pack8(AH), am = pack8(AM), al = pack8(AL);
      accH = MFMA(ah, wr[kt][0], accH);
      accC = MFMA(ah, wr[kt][1], accC);
      accC = MFMA(am, wr[kt][0], accC);
      accC = MFMA(am, wr[kt][1], accC);
      accC = MFMA(ah, wr[kt][2], accC);
      accC = MFMA(al, wr[kt][0], accC);
    }
    // partial logits (x64 scale kept; reducer unscales)
    {
      const size_t trow = tokbase + (size_t)i * 32 + th * 16 + (lane >> 4) * 4;
      float* pw = parts + ((size_t)ks * NTOK + trow) * 64 + eq * 16 + (lane & 15);
#pragma unroll
      for (int r = 0; r < 4; ++r) pw[(size_t)r * 64] = accH[r] + accC[r];
    }
    __builtin_amdgcn_s_barrier();
  }
}

// per-token finisher: sum 16 k-partials (fixed order), softmax, top-8,
// pi/ce reductions. 1 wave per block, token = blockIdx*64 + lane.
__global__ __launch_bounds__(64) void reduce_fin(
    const float* __restrict__ parts, float* __restrict__ out,
    float* __restrict__ pi_g, float* __restrict__ ce_g, int N) {
  __shared__ float hist[64];
  const int lane = threadIdx.x;
  const size_t t = (size_t)blockIdx.x * 64 + lane;

  f32x4 a[16];
#pragma unroll
  for (int s = 0; s < KSPLIT; ++s) {
    const float* p = parts + ((size_t)s * NTOK + t) * 64;
#pragma unroll
    for (int c = 0; c < 16; ++c) {
      const f32x4 v = *(const f32x4*)(p + c * 4);
      if (s == 0) a[c] = v; else a[c] += v;
    }
  }
  float m = -1e30f;
#pragma unroll
  for (int c = 0; c < 16; ++c) {
    a[c] *= 0.015625f;  // undo w x64 prescale
    m = fmaxf(m, fmaxf(fmaxf(a[c][0], a[c][1]), fmaxf(a[c][2], a[c][3])));
  }
  // top-8 on raw logits (strict > keeps lowest index on ties, descending)
  unsigned long long used = 0ull;
  float bvs[8];
  int bis[8];
#pragma unroll
  for (int r = 0; r < 8; ++r) {
    float bv = -1e30f;
    int bi = 0;
#pragma unroll
    for (int c = 0; c < 16; ++c)
#pragma unroll
      for (int j = 0; j < 4; ++j) {
        const int e = c * 4 + j;
        const float v = ((used >> e) & 1ull) ? -1e30f : a[c][j];
        if (v > bv) { bv = v; bi = e; }
      }
    used |= (1ull << bi);
    bvs[r] = bv;
    bis[r] = bi;
  }
  // softmax denominator + p values (overwrite a)
  float ssum = 0.f;
#pragma unroll
  for (int c = 0; c < 16; ++c)
#pragma unroll
    for (int j = 0; j < 4; ++j) {
      a[c][j] = expf(a[c][j] - m);
      ssum += a[c][j];
    }
  const float inv = 1.f / ssum;

  // outputs
  f32x4 o0, o1, w0, w1;
#pragma unroll
  for (int r = 0; r < 4; ++r) {
    o0[r] = (float)bis[r];
    o1[r] = (float)bis[r + 4];
    w0[r] = expf(bvs[r] - m) * inv;
    w1[r] = expf(bvs[r + 4] - m) * inv;
  }
  *(f32x4*)(out + t * 8) = o0;
  *(f32x4*)(out + t * 8 + 4) = o1;
  *(f32x4*)(out + (size_t)N * 8 + t * 8) = w0;
  *(f32x4*)(out + (size_t)N * 8 + t * 8 + 4) = w1;

  // pi: per-expert mean-score partial (wave-reduce then one atomic)
#pragma unroll
  for (int c = 0; c < 16; ++c)
#pragma unroll
    for (int j = 0; j < 4; ++j) {
      float v = a[c][j] * inv;
#pragma unroll
      for (int off = 32; off; off >>= 1) v += __shfl_xor(v, off, 64);
      if (lane == 0) atomicAdd(pi_g + (c * 4 + j), v);
    }
  // ce: top-8 histogram
  hist[lane] = 0.f;
  __syncthreads();
#pragma unroll
  for (int r = 0; r < 8; ++r) atomicAdd(&hist[bis[r]], 1.f);
  __syncthreads();
  atomicAdd(ce_g + lane, hist[lane]);
}

// w [64][4096] -> fragment-ordered 3-way split blob, scaled by 64
__global__ void build_wfrag(const float* __restrict__ w,
                            ushort* __restrict__ wf) {
  const int kb = blockIdx.x;  // 0..127
  const int t = threadIdx.x;  // 256
  const int eg = t >> 6, lane = t & 63;
  const int e = (eg << 4) + (lane & 15);
  const int k0 = (kb << 5) + ((lane >> 4) << 3);
  const float* src = w + (size_t)e * DDIM + k0;
  unsigned H[4], M[4], L[4];
#pragma unroll
  for (int i = 0; i < 4; ++i) {
    float a = src[2 * i] * 64.f, b = src[2 * i + 1] * 64.f;
    split2(a, b, H[i], M[i], L[i]);
  }
  const size_t base = ((size_t)kb * 12 + eg * 3) * 512 + (size_t)lane * 8;
  *(uint4*)(wf + base) = make_uint4(H[0], H[1], H[2], H[3]);
  *(uint4*)(wf + base + 512) = make_uint4(M[0], M[1], M[2], M[3]);
  *(uint4*)(wf + base + 1024) = make_uint4(L[0], L[1], L[2], L[3]);
}

__global__ void aux_final(const float* __restrict__ pi_g,
                          const float* __restrict__ ce_g,
                          float* __restrict__ out_aux, int N) {
  const int e = threadIdx.x;  // 64
  float v = (pi_g[e] / (float)N) * (ce_g[e] / ((float)N * 8.0f)) * 64.0f * 0.01f;
#pragma unroll
  for (int off = 32; off; off >>= 1) v += __shfl_down(v, off, 64);
  if (e == 0) *out_aux = v;
}

extern "C" void kernel_launch(void* const* d_in, const int* in_sizes, int n_in,
                              void* d_out, int out_size, void* d_ws,
                              size_t ws_size, hipStream_t stream) {
  (void)n_in; (void)out_size; (void)ws_size;
  const float* x = (const float*)d_in[0];
  const float* w = (const float*)d_in[1];
  float* out = (float*)d_out;
  const int N = in_sizes[0] / DDIM;  // 16384

  ushort* wf = (ushort*)d_ws;                            // 1.5 MiB @ 0
  float* parts = (float*)((char*)d_ws + (2u << 20));     // 64 MiB
  float* pi_g = (float*)((char*)d_ws + (2u << 20) + (size_t)KSPLIT * NTOK * 64 * 4);
  float* ce_g = pi_g + 64;

  hipMemsetAsync(pi_g, 0, 128 * sizeof(float), stream);
  build_wfrag<<<128, 256, 0, stream>>>(w, wf);
  moe_gemm<<<256, 512, 0, stream>>>(x, wf, parts);
  reduce_fin<<<NTOK / 64, 64, 0, stream>>>(parts, out, pi_g, ce_g, N);
  aux_final<<<1, 64, 0, stream>>>(pi_g, ce_g, out + (size_t)N * 16, N);
}

// Round 13
// 255.552 us; speedup vs baseline: 1.0023x; 1.0023x over previous
//
#include <hip/hip_runtime.h>
#include <math.h>

#define DDIM 4096
#define NEXP 64
#define KSPLIT 16
#define KRANGE 256  // k per block
#define NKT 8       // 32-k tiles per block
#define TGTOK 1024  // tokens per block
#define NSTEP 32    // token steps of 32
#define XCH 32768   // one x buffer: 32 tok x 1KB
#define NTOK 16384

typedef short s16x8 __attribute__((ext_vector_type(8)));
typedef float f32x4 __attribute__((ext_vector_type(4)));

__device__ __forceinline__ unsigned cvt_pk_bf16(float a, float b) {
  unsigned r;
  asm("v_cvt_pk_bf16_f32 %0, %1, %2" : "=v"(r) : "v"(a), "v"(b));
  return r;
}

__device__ __forceinline__ void split2(float a, float b, unsigned& H,
                                       unsigned& M, unsigned& L) {
  H = cvt_pk_bf16(a, b);
  float h0 = __uint_as_float(H << 16);
  float h1 = __uint_as_float(H & 0xffff0000u);
  float r0 = a - h0, r1 = b - h1;
  M = cvt_pk_bf16(r0, r1);
  float m0 = __uint_as_float(M << 16);
  float m1 = __uint_as_float(M & 0xffff0000u);
  L = cvt_pk_bf16(r0 - m0, r1 - m1);
}

union U8 { unsigned u[4]; s16x8 v; };
__device__ __forceinline__ s16x8 pack8(const unsigned* a) {
  U8 t;
  t.u[0] = a[0]; t.u[1] = a[1]; t.u[2] = a[2]; t.u[3] = a[3];
  return t.v;
}

#define MFMA(A, B, C) __builtin_amdgcn_mfma_f32_16x16x32_bf16(A, B, C, 0, 0, 0)

// stage 32 tokens' contiguous 1KB k-slices; one DMA per token; source
// chunk-XOR-swizzled (rule #21) so swizzled LDS reads are conflict-balanced.
__device__ __forceinline__ void stage_tok(const float* __restrict__ x,
                                          char* dst, size_t tokbase, int ks,
                                          int step, int wv, int lane) {
#pragma unroll
  for (int j = 0; j < 4; ++j) {
    const int t32 = wv * 4 + j;
    const float* src = x + (tokbase + (size_t)step * 32 + t32) * DDIM +
                       ks * KRANGE + ((lane ^ (t32 & 7)) << 2);
    __builtin_amdgcn_global_load_lds(
        (const __attribute__((address_space(1))) void*)src,
        (__attribute__((address_space(3))) void*)(dst + t32 * 1024), 16, 0, 0);
  }
}

// 256 blocks (16 ks x 16 tg), 512 thr (8 waves). Wave (th = wv>>2, eq = wv&3):
// 16 tokens x 16 experts x 256 k per step. w fragments PERSISTENT in VGPRs
// (24 frags = 96 VGPR, loaded once) -> zero w traffic in loop. x staged via
// global_load_lds, depth-2 prefetch, triple buffer, counted vmcnt(12).
// Per-step 16x16 logit partials written to parts[ks][token][expert].
__global__ __launch_bounds__(512, 2) void moe_gemm(
    const float* __restrict__ x, const ushort* __restrict__ wf,
    float* __restrict__ parts) {
  __shared__ char xls[3 * XCH];  // 96 KB
  const int tid = threadIdx.x;
  const int lane = tid & 63;
  const int wv = tid >> 6;  // 0..7
  const int th = wv >> 2;   // token half of the 32-token step chunk
  const int eq = wv & 3;    // expert quarter
  const int bid = blockIdx.x;
  const int ks = bid & 15;
  const size_t tokbase = (size_t)(bid >> 4) * TGTOK;

  // prologue: 2 steps of x in flight FIRST (oldest), then w-frag loads
  stage_tok(x, xls, tokbase, ks, 0, wv, lane);
  stage_tok(x, xls + XCH, tokbase, ks, 1, wv, lane);

  s16x8 wr[NKT][3];  // persistent w fragments (static indexing only)
  {
    const ushort* wbase =
        wf + ((size_t)(ks * NKT) * 12 + eq * 3) * 512 + lane * 8;
#pragma unroll
    for (int kt = 0; kt < NKT; ++kt)
#pragma unroll
      for (int l = 0; l < 3; ++l)
        wr[kt][l] = *(const s16x8*)(wbase + ((size_t)kt * 12 + l) * 512);
  }

  const int trd = th * 16 + (lane & 15);  // token read by this lane
  const int sz = trd & 7;
  const int coff = (lane >> 4) * 2;  // k-octet chunk offset

#pragma unroll 1
  for (int i = 0; i < NSTEP; ++i) {
    if (i < NSTEP - 2) {
      stage_tok(x, xls + ((i + 2) % 3) * XCH, tokbase, ks, i + 2, wv, lane);
      asm volatile("s_waitcnt vmcnt(12)" ::: "memory");
    } else if (i == NSTEP - 2) {
      asm volatile("s_waitcnt vmcnt(8)" ::: "memory");
    } else {
      asm volatile("s_waitcnt vmcnt(4)" ::: "memory");
    }
    __builtin_amdgcn_s_barrier();

    const char* xrow = xls + (i % 3) * XCH + trd * 1024;
    f32x4 accH = {0.f, 0.f, 0.f, 0.f}, accC = {0.f, 0.f, 0.f, 0.f};
#pragma unroll
    for (int kt = 0; kt < NKT; ++kt) {
      const int c0 = kt * 8 + coff;
      const f32x4 xa = *(const f32x4*)(xrow + ((c0 ^ sz) << 4));
      const f32x4 xv = *(const f32x4*)(xrow + (((c0 + 1) ^ sz) << 4));
      unsigned AH[4], AM[4], AL[4];
      split2(xa[0], xa[1], AH[0], AM[0], AL[0]);
      split2(xa[2], xa[3], AH[1], AM[1], AL[1]);
      split2(xv[0], xv[1], AH[2], AM[2], AL[2]);
      split2(xv[2], xv[3], AH[3], AM[3], AL[3]);
      const s16x8 ah = pack8(AH), am = pack8(AM), al = pack8(AL);
      accH = MFMA(ah, wr[kt][0], accH);
      accC = MFMA(ah, wr[kt][1], accC);
      accC = MFMA(am, wr[kt][0], accC);
      accC = MFMA(am, wr[kt][1], accC);
      accC = MFMA(ah, wr[kt][2], accC);
      accC = MFMA(al, wr[kt][0], accC);
    }
    // partial logits (x64 scale kept; reducer unscales)
    {
      const size_t trow = tokbase + (size_t)i * 32 + th * 16 + (lane >> 4) * 4;
      float* pw = parts + ((size_t)ks * NTOK + trow) * 64 + eq * 16 + (lane & 15);
#pragma unroll
      for (int r = 0; r < 4; ++r) pw[(size_t)r * 64] = accH[r] + accC[r];
    }
    __builtin_amdgcn_s_barrier();
  }
}

// per-token finisher: sum 16 k-partials (fixed order), softmax, top-8,
// pi/ce reductions. 1 wave per block, token = blockIdx*64 + lane.
__global__ __launch_bounds__(64) void reduce_fin(
    const float* __restrict__ parts, float* __restrict__ out,
    float* __restrict__ pi_g, float* __restrict__ ce_g, int N) {
  __shared__ float hist[64];
  const int lane = threadIdx.x;
  const size_t t = (size_t)blockIdx.x * 64 + lane;

  f32x4 a[16];
#pragma unroll
  for (int s = 0; s < KSPLIT; ++s) {
    const float* p = parts + ((size_t)s * NTOK + t) * 64;
#pragma unroll
    for (int c = 0; c < 16; ++c) {
      const f32x4 v = *(const f32x4*)(p + c * 4);
      if (s == 0) a[c] = v; else a[c] += v;
    }
  }
  float m = -1e30f;
#pragma unroll
  for (int c = 0; c < 16; ++c) {
    a[c] *= 0.015625f;  // undo w x64 prescale
    m = fmaxf(m, fmaxf(fmaxf(a[c][0], a[c][1]), fmaxf(a[c][2], a[c][3])));
  }
  // top-8 on raw logits (strict > keeps lowest index on ties, descending)
  unsigned long long used = 0ull;
  float bvs[8];
  int bis[8];
#pragma unroll
  for (int r = 0; r < 8; ++r) {
    float bv = -1e30f;
    int bi = 0;
#pragma unroll
    for (int c = 0; c < 16; ++c)
#pragma unroll
      for (int j = 0; j < 4; ++j) {
        const int e = c * 4 + j;
        const float v = ((used >> e) & 1ull) ? -1e30f : a[c][j];
        if (v > bv) { bv = v; bi = e; }
      }
    used |= (1ull << bi);
    bvs[r] = bv;
    bis[r] = bi;
  }
  // softmax denominator + p values (overwrite a)
  float ssum = 0.f;
#pragma unroll
  for (int c = 0; c < 16; ++c)
#pragma unroll
    for (int j = 0; j < 4; ++j) {
      a[c][j] = expf(a[c][j] - m);
      ssum += a[c][j];
    }
  const float inv = 1.f / ssum;

  // outputs
  f32x4 o0, o1, w0, w1;
#pragma unroll
  for (int r = 0; r < 4; ++r) {
    o0[r] = (float)bis[r];
    o1[r] = (float)bis[r + 4];
    w0[r] = expf(bvs[r] - m) * inv;
    w1[r] = expf(bvs[r + 4] - m) * inv;
  }
  *(f32x4*)(out + t * 8) = o0;
  *(f32x4*)(out + t * 8 + 4) = o1;
  *(f32x4*)(out + (size_t)N * 8 + t * 8) = w0;
  *(f32x4*)(out + (size_t)N * 8 + t * 8 + 4) = w1;

  // pi: per-expert mean-score partial (wave-reduce then one atomic)
#pragma unroll
  for (int c = 0; c < 16; ++c)
#pragma unroll
    for (int j = 0; j < 4; ++j) {
      float v = a[c][j] * inv;
#pragma unroll
      for (int off = 32; off; off >>= 1) v += __shfl_xor(v, off, 64);
      if (lane == 0) atomicAdd(pi_g + (c * 4 + j), v);
    }
  // ce: top-8 histogram
  hist[lane] = 0.f;
  __syncthreads();
#pragma unroll
  for (int r = 0; r < 8; ++r) atomicAdd(&hist[bis[r]], 1.f);
  __syncthreads();
  atomicAdd(ce_g + lane, hist[lane]);
}

// w [64][4096] -> fragment-ordered 3-way split blob, scaled by 64
__global__ void build_wfrag(const float* __restrict__ w,
                            ushort* __restrict__ wf) {
  const int kb = blockIdx.x;  // 0..127
  const int t = threadIdx.x;  // 256
  const int eg = t >> 6, lane = t & 63;
  const int e = (eg << 4) + (lane & 15);
  const int k0 = (kb << 5) + ((lane >> 4) << 3);
  const float* src = w + (size_t)e * DDIM + k0;
  unsigned H[4], M[4], L[4];
#pragma unroll
  for (int i = 0; i < 4; ++i) {
    float a = src[2 * i] * 64.f, b = src[2 * i + 1] * 64.f;
    split2(a, b, H[i], M[i], L[i]);
  }
  const size_t base = ((size_t)kb * 12 + eg * 3) * 512 + (size_t)lane * 8;
  *(uint4*)(wf + base) = make_uint4(H[0], H[1], H[2], H[3]);
  *(uint4*)(wf + base + 512) = make_uint4(M[0], M[1], M[2], M[3]);
  *(uint4*)(wf + base + 1024) = make_uint4(L[0], L[1], L[2], L[3]);
}

__global__ void aux_final(const float* __restrict__ pi_g,
                          const float* __restrict__ ce_g,
                          float* __restrict__ out_aux, int N) {
  const int e = threadIdx.x;  // 64
  float v = (pi_g[e] / (float)N) * (ce_g[e] / ((float)N * 8.0f)) * 64.0f * 0.01f;
#pragma unroll
  for (int off = 32; off; off >>= 1) v += __shfl_down(v, off, 64);
  if (e == 0) *out_aux = v;
}

extern "C" void kernel_launch(void* const* d_in, const int* in_sizes, int n_in,
                              void* d_out, int out_size, void* d_ws,
                              size_t ws_size, hipStream_t stream) {
  (void)n_in; (void)out_size; (void)ws_size;
  const float* x = (const float*)d_in[0];
  const float* w = (const float*)d_in[1];
  float* out = (float*)d_out;
  const int N = in_sizes[0] / DDIM;  // 16384

  ushort* wf = (ushort*)d_ws;                            // 1.5 MiB @ 0
  float* parts = (float*)((char*)d_ws + (2u << 20));     // 64 MiB
  float* pi_g = (float*)((char*)d_ws + (2u << 20) + (size_t)KSPLIT * NTOK * 64 * 4);
  float* ce_g = pi_g + 64;

  hipMemsetAsync(pi_g, 0, 128 * sizeof(float), stream);
  build_wfrag<<<128, 256, 0, stream>>>(w, wf);
  moe_gemm<<<256, 512, 0, stream>>>(x, wf, parts);
  reduce_fin<<<NTOK / 64, 64, 0, stream>>>(parts, out, pi_g, ce_g, N);
  aux_final<<<1, 64, 0, stream>>>(pi_g, ce_g, out + (size_t)N * 16, N);
}

// Round 14
// 247.101 us; speedup vs baseline: 1.0366x; 1.0342x over previous
//
#include <hip/hip_runtime.h>
#include <math.h>

#define DDIM 4096
#define NEXP 64
#define KSPLIT 16
#define KRANGE 256  // k per block
#define NKT 8       // 32-k tiles per block
#define TGTOK 1024  // tokens per block
#define NSTEP 32    // token steps of 32
#define XCH 32768   // one x buffer: 32 tok x 1KB
#define NTOK 16384

typedef short s16x8 __attribute__((ext_vector_type(8)));
typedef float f32x4 __attribute__((ext_vector_type(4)));

__device__ __forceinline__ unsigned cvt_pk_bf16(float a, float b) {
  unsigned r;
  asm("v_cvt_pk_bf16_f32 %0, %1, %2" : "=v"(r) : "v"(a), "v"(b));
  return r;
}

__device__ __forceinline__ void split2(float a, float b, unsigned& H,
                                       unsigned& M, unsigned& L) {
  H = cvt_pk_bf16(a, b);
  float h0 = __uint_as_float(H << 16);
  float h1 = __uint_as_float(H & 0xffff0000u);
  float r0 = a - h0, r1 = b - h1;
  M = cvt_pk_bf16(r0, r1);
  float m0 = __uint_as_float(M << 16);
  float m1 = __uint_as_float(M & 0xffff0000u);
  L = cvt_pk_bf16(r0 - m0, r1 - m1);
}

union U8 { unsigned u[4]; s16x8 v; };
__device__ __forceinline__ s16x8 pack8(const unsigned* a) {
  U8 t;
  t.u[0] = a[0]; t.u[1] = a[1]; t.u[2] = a[2]; t.u[3] = a[3];
  return t.v;
}

#define MFMA(A, B, C) __builtin_amdgcn_mfma_f32_16x16x32_bf16(A, B, C, 0, 0, 0)

// stage 32 tokens' contiguous 1KB k-slices; one DMA per token; source
// chunk-XOR-swizzled (rule #21) so swizzled LDS reads are conflict-balanced.
__device__ __forceinline__ void stage_tok(const float* __restrict__ x,
                                          char* dst, size_t tokbase, int ks,
                                          int step, int wv, int lane) {
#pragma unroll
  for (int j = 0; j < 4; ++j) {
    const int t32 = wv * 4 + j;
    const float* src = x + (tokbase + (size_t)step * 32 + t32) * DDIM +
                       ks * KRANGE + ((lane ^ (t32 & 7)) << 2);
    __builtin_amdgcn_global_load_lds(
        (const __attribute__((address_space(1))) void*)src,
        (__attribute__((address_space(3))) void*)(dst + t32 * 1024), 16, 0, 0);
  }
}

// 256 blocks (16 ks x 16 tg), 512 thr (8 waves). Wave (th = wv>>2, eq = wv&3):
// 16 tokens x 16 experts x 256 k per step. w fragments PERSISTENT in VGPRs
// (24 frags = 96 VGPR, loaded once) -> zero w traffic in loop. x staged via
// global_load_lds, depth-2 prefetch, triple buffer, counted vmcnt(12).
// Per-step 16x16 logit partials written to parts[ks][token][expert].
__global__ __launch_bounds__(512, 2) void moe_gemm(
    const float* __restrict__ x, const ushort* __restrict__ wf,
    float* __restrict__ parts) {
  __shared__ char xls[3 * XCH];  // 96 KB
  const int tid = threadIdx.x;
  const int lane = tid & 63;
  const int wv = tid >> 6;  // 0..7
  const int th = wv >> 2;   // token half of the 32-token step chunk
  const int eq = wv & 3;    // expert quarter
  const int bid = blockIdx.x;
  const int ks = bid & 15;
  const size_t tokbase = (size_t)(bid >> 4) * TGTOK;

  // prologue: 2 steps of x in flight FIRST (oldest), then w-frag loads
  stage_tok(x, xls, tokbase, ks, 0, wv, lane);
  stage_tok(x, xls + XCH, tokbase, ks, 1, wv, lane);

  s16x8 wr[NKT][3];  // persistent w fragments (static indexing only)
  {
    const ushort* wbase =
        wf + ((size_t)(ks * NKT) * 12 + eq * 3) * 512 + lane * 8;
#pragma unroll
    for (int kt = 0; kt < NKT; ++kt)
#pragma unroll
      for (int l = 0; l < 3; ++l)
        wr[kt][l] = *(const s16x8*)(wbase + ((size_t)kt * 12 + l) * 512);
  }

  const int trd = th * 16 + (lane & 15);  // token read by this lane
  const int sz = trd & 7;
  const int coff = (lane >> 4) * 2;  // k-octet chunk offset

#pragma unroll 1
  for (int i = 0; i < NSTEP; ++i) {
    if (i < NSTEP - 2) {
      stage_tok(x, xls + ((i + 2) % 3) * XCH, tokbase, ks, i + 2, wv, lane);
      asm volatile("s_waitcnt vmcnt(12)" ::: "memory");
    } else if (i == NSTEP - 2) {
      asm volatile("s_waitcnt vmcnt(8)" ::: "memory");
    } else {
      asm volatile("s_waitcnt vmcnt(4)" ::: "memory");
    }
    __builtin_amdgcn_s_barrier();

    const char* xrow = xls + (i % 3) * XCH + trd * 1024;
    f32x4 accH = {0.f, 0.f, 0.f, 0.f}, accC = {0.f, 0.f, 0.f, 0.f};
#pragma unroll
    for (int kt = 0; kt < NKT; ++kt) {
      const int c0 = kt * 8 + coff;
      const f32x4 xa = *(const f32x4*)(xrow + ((c0 ^ sz) << 4));
      const f32x4 xv = *(const f32x4*)(xrow + (((c0 + 1) ^ sz) << 4));
      unsigned AH[4], AM[4], AL[4];
      split2(xa[0], xa[1], AH[0], AM[0], AL[0]);
      split2(xa[2], xa[3], AH[1], AM[1], AL[1]);
      split2(xv[0], xv[1], AH[2], AM[2], AL[2]);
      split2(xv[2], xv[3], AH[3], AM[3], AL[3]);
      const s16x8 ah = pack8(AH), am = pack8(AM), al = pack8(AL);
      accH = MFMA(ah, wr[kt][0], accH);
      accC = MFMA(ah, wr[kt][1], accC);
      accC = MFMA(am, wr[kt][0], accC);
      accC = MFMA(am, wr[kt][1], accC);
      accC = MFMA(ah, wr[kt][2], accC);
      accC = MFMA(al, wr[kt][0], accC);
    }
    // partial logits (x64 scale kept; sum_parts unscales)
    {
      const size_t trow = tokbase + (size_t)i * 32 + th * 16 + (lane >> 4) * 4;
      float* pw = parts + ((size_t)ks * NTOK + trow) * 64 + eq * 16 + (lane & 15);
#pragma unroll
      for (int r = 0; r < 4; ++r) pw[(size_t)r * 64] = accH[r] + accC[r];
    }
    __builtin_amdgcn_s_barrier();
  }
}

// stage 1: sum the 16 k-partials with full-chip parallelism.
// thread = one f32x4 of the [16384][64] logit matrix. 64MB read (L3-hot),
// 4MB write. Fixed summation order (deterministic).
__global__ __launch_bounds__(256) void sum_parts(const float* __restrict__ parts,
                                                 float* __restrict__ logits) {
  const size_t idx = (size_t)blockIdx.x * 256 + threadIdx.x;  // f32x4 units
  const f32x4* p = (const f32x4*)parts;
  f32x4 a = p[idx];
#pragma unroll
  for (int s = 1; s < KSPLIT; ++s) a += p[(size_t)s * (NTOK * 16) + idx];
  ((f32x4*)logits)[idx] = a * 0.015625f;  // undo w x64 prescale
}

// stage 2: per-token finisher on the summed logits (256B/lane, L3-hot):
// softmax, stable top-8, pi/ce reductions. token = blockIdx*64 + lane.
__global__ __launch_bounds__(64) void fin(const float* __restrict__ logits,
                                          float* __restrict__ out,
                                          float* __restrict__ pi_g,
                                          float* __restrict__ ce_g, int N) {
  __shared__ float hist[64];
  const int lane = threadIdx.x;
  const size_t t = (size_t)blockIdx.x * 64 + lane;

  f32x4 a[16];
  {
    const f32x4* p = (const f32x4*)(logits + t * 64);
#pragma unroll
    for (int c = 0; c < 16; ++c) a[c] = p[c];
  }
  float m = -1e30f;
#pragma unroll
  for (int c = 0; c < 16; ++c)
    m = fmaxf(m, fmaxf(fmaxf(a[c][0], a[c][1]), fmaxf(a[c][2], a[c][3])));

  // top-8 on raw logits (strict > keeps lowest index on ties, descending)
  unsigned long long used = 0ull;
  float bvs[8];
  int bis[8];
#pragma unroll
  for (int r = 0; r < 8; ++r) {
    float bv = -1e30f;
    int bi = 0;
#pragma unroll
    for (int c = 0; c < 16; ++c)
#pragma unroll
      for (int j = 0; j < 4; ++j) {
        const int e = c * 4 + j;
        const float v = ((used >> e) & 1ull) ? -1e30f : a[c][j];
        if (v > bv) { bv = v; bi = e; }
      }
    used |= (1ull << bi);
    bvs[r] = bv;
    bis[r] = bi;
  }
  // softmax denominator + p values (overwrite a)
  float ssum = 0.f;
#pragma unroll
  for (int c = 0; c < 16; ++c)
#pragma unroll
    for (int j = 0; j < 4; ++j) {
      a[c][j] = expf(a[c][j] - m);
      ssum += a[c][j];
    }
  const float inv = 1.f / ssum;

  // outputs
  f32x4 o0, o1, w0, w1;
#pragma unroll
  for (int r = 0; r < 4; ++r) {
    o0[r] = (float)bis[r];
    o1[r] = (float)bis[r + 4];
    w0[r] = expf(bvs[r] - m) * inv;
    w1[r] = expf(bvs[r + 4] - m) * inv;
  }
  *(f32x4*)(out + t * 8) = o0;
  *(f32x4*)(out + t * 8 + 4) = o1;
  *(f32x4*)(out + (size_t)N * 8 + t * 8) = w0;
  *(f32x4*)(out + (size_t)N * 8 + t * 8 + 4) = w1;

  // pi: per-expert mean-score partial (wave-reduce then one atomic)
#pragma unroll
  for (int c = 0; c < 16; ++c)
#pragma unroll
    for (int j = 0; j < 4; ++j) {
      float v = a[c][j] * inv;
#pragma unroll
      for (int off = 32; off; off >>= 1) v += __shfl_xor(v, off, 64);
      if (lane == 0) atomicAdd(pi_g + (c * 4 + j), v);
    }
  // ce: top-8 histogram
  hist[lane] = 0.f;
  __syncthreads();
#pragma unroll
  for (int r = 0; r < 8; ++r) atomicAdd(&hist[bis[r]], 1.f);
  __syncthreads();
  atomicAdd(ce_g + lane, hist[lane]);
}

// w [64][4096] -> fragment-ordered 3-way split blob, scaled by 64
__global__ void build_wfrag(const float* __restrict__ w,
                            ushort* __restrict__ wf) {
  const int kb = blockIdx.x;  // 0..127
  const int t = threadIdx.x;  // 256
  const int eg = t >> 6, lane = t & 63;
  const int e = (eg << 4) + (lane & 15);
  const int k0 = (kb << 5) + ((lane >> 4) << 3);
  const float* src = w + (size_t)e * DDIM + k0;
  unsigned H[4], M[4], L[4];
#pragma unroll
  for (int i = 0; i < 4; ++i) {
    float a = src[2 * i] * 64.f, b = src[2 * i + 1] * 64.f;
    split2(a, b, H[i], M[i], L[i]);
  }
  const size_t base = ((size_t)kb * 12 + eg * 3) * 512 + (size_t)lane * 8;
  *(uint4*)(wf + base) = make_uint4(H[0], H[1], H[2], H[3]);
  *(uint4*)(wf + base + 512) = make_uint4(M[0], M[1], M[2], M[3]);
  *(uint4*)(wf + base + 1024) = make_uint4(L[0], L[1], L[2], L[3]);
}

__global__ void aux_final(const float* __restrict__ pi_g,
                          const float* __restrict__ ce_g,
                          float* __restrict__ out_aux, int N) {
  const int e = threadIdx.x;  // 64
  float v = (pi_g[e] / (float)N) * (ce_g[e] / ((float)N * 8.0f)) * 64.0f * 0.01f;
#pragma unroll
  for (int off = 32; off; off >>= 1) v += __shfl_down(v, off, 64);
  if (e == 0) *out_aux = v;
}

extern "C" void kernel_launch(void* const* d_in, const int* in_sizes, int n_in,
                              void* d_out, int out_size, void* d_ws,
                              size_t ws_size, hipStream_t stream) {
  (void)n_in; (void)out_size; (void)ws_size;
  const float* x = (const float*)d_in[0];
  const float* w = (const float*)d_in[1];
  float* out = (float*)d_out;
  const int N = in_sizes[0] / DDIM;  // 16384

  ushort* wf = (ushort*)d_ws;                         // 1.5 MiB @ 0
  float* parts = (float*)((char*)d_ws + (2u << 20));  // 64 MiB
  float* logits = (float*)((char*)d_ws + (2u << 20) +
                           (size_t)KSPLIT * NTOK * 64 * 4);  // 4 MiB
  float* pi_g = logits + (size_t)NTOK * 64;
  float* ce_g = pi_g + 64;

  hipMemsetAsync(pi_g, 0, 128 * sizeof(float), stream);
  build_wfrag<<<128, 256, 0, stream>>>(w, wf);
  moe_gemm<<<256, 512, 0, stream>>>(x, wf, parts);
  sum_parts<<<NTOK * 16 / 256, 256, 0, stream>>>(parts, logits);
  fin<<<NTOK / 64, 64, 0, stream>>>(logits, out, pi_g, ce_g, N);
  aux_final<<<1, 64, 0, stream>>>(pi_g, ce_g, out + (size_t)N * 16, N);
}